// Round 6
// baseline (394.666 us; speedup 1.0000x reference)
//
#include <hip/hip_runtime.h>

// dims: L=64, CH=16, PIX=256, PAT=64, RC=32, BD=64, OUT=10, B=256
// inputs: 0=x(256,64,256,16) 1=chi_first(32,16) 2=chi_mid(62,32,32,16)
// 3=chi_last(32,16,10) 4=psi_first(64,256) 5=psi_mid(62,64,64,256)
// 6=psi_last(64,256) 7=phi_first(64,64) 8=phi_mid(62,64,64,64) 9=phi_last(64,64)

static inline int imin(int a, int b) { return a < b ? a : b; }

typedef __attribute__((ext_vector_type(8))) short bf16x8;          // 8 bf16 (4 VGPR)
typedef __attribute__((ext_vector_type(8))) unsigned short us8;
typedef __attribute__((ext_vector_type(4))) float f32x4;

__device__ __forceinline__ unsigned short f2bf(float v) {
  union { float f; unsigned int u; } c; c.f = v;
  unsigned int u = c.u;
  unsigned int r = (u + 0x7fffu + ((u >> 16) & 1u)) >> 16;  // RTN-even
  return (unsigned short)r;
}
__device__ __forceinline__ float bf2f(unsigned short h) {
  union { unsigned int u; float f; } c; c.u = ((unsigned int)h) << 16;
  return c.f;
}

// ---------------------------------------------------------------------------
// K1: vpx means + bf16 hi/lo fragment emit. Fused: blocks >= 16384 do the
// phi slice gather (slices[i][l*64+r] = phi_mid[i][l][r][i+1]).
__global__ __launch_bounds__(256) void k_reduce_x(const float* __restrict__ x,
                                                  float* __restrict__ vch,
                                                  float* __restrict__ vpx,
                                                  unsigned short* __restrict__ vpxf_hi,
                                                  unsigned short* __restrict__ vpxf_lo,
                                                  const float* __restrict__ phi_mid,
                                                  float* __restrict__ slices) {
  if (blockIdx.x >= 16384) {                 // phi gather block
    int i = blockIdx.x - 16384;              // 0..61
    int t = threadIdx.x;
    #pragma unroll
    for (int k = 0; k < 16; ++k) {
      int idx = t + k * 256;                 // l*64 + r
      slices[(size_t)i * 4096 + idx] = phi_mid[((size_t)i * 4096 + idx) * 64 + (i + 1)];
    }
    return;
  }
  int bp = blockIdx.x;             // b*64 + s
  int b = bp >> 6, s = bp & 63;
  int q = threadIdx.x;             // = p
  const float* row = x + ((size_t)bp << 12) + q * 16;
  float4 r0 = *(const float4*)(row);
  float4 r1 = *(const float4*)(row + 4);
  float4 r2 = *(const float4*)(row + 8);
  float4 r3 = *(const float4*)(row + 12);
  float csum = r0.x + r0.y + r0.z + r0.w + r1.x + r1.y + r1.z + r1.w
             + r2.x + r2.y + r2.z + r2.w + r3.x + r3.y + r3.z + r3.w;
  float val = csum * (1.0f / 16.0f);
  if (vpx && (s == 0 || s == 63)) vpx[((size_t)s * 256 + b) * 256 + q] = val;
  if (vpxf_hi && s >= 1 && s <= 62) {
    unsigned short hb = f2bf(val);
    unsigned short lb = f2bf(val - bf2f(hb));
    size_t fa = (size_t)s * 65536
              + (((size_t)(q >> 5) * 16 + (b >> 4)) * 64 + (((q >> 3) & 3) * 16 + (b & 15))) * 8
              + (q & 7);
    vpxf_hi[fa] = hb;
    vpxf_lo[fa] = lb;
  }

  __shared__ float sc[256][20];
  *(float4*)&sc[q][0]  = r0;
  *(float4*)&sc[q][4]  = r1;
  *(float4*)&sc[q][8]  = r2;
  *(float4*)&sc[q][12] = r3;
  __syncthreads();
  int c = q & 15, g = q >> 4;
  float ps = 0.f;
  #pragma unroll
  for (int k = 0; k < 16; ++k) ps += sc[g * 16 + k][c];
  __shared__ float p2[16][17];
  p2[g][c] = ps;
  __syncthreads();
  if (q < 16) {
    float s2 = 0.f;
    #pragma unroll
    for (int k = 0; k < 16; ++k) s2 += p2[k][q];
    vch[((size_t)s * 256 + b) * 16 + q] = s2 * (1.0f / 256.0f);
  }
}

// ---------------------------------------------------------------------------
// K2 (MFMA): M[z][b][lr] = sum_p W[s][lr][p] * vpx[s+1][b][p], hi/lo bf16.
// 512 threads / 8 waves; wave w owns b-tiles bt = w*2+{0,1} (32 b) x 64 lr.
// acc[2][4] = 32 VGPR -> total ~100 VGPR, no launch_bounds cap, NO SPILL.
// Same verified LDS fragment layout as r3; double-buffered issue-early stage.
__global__ __launch_bounds__(512) void k_psi_gemm(const float* __restrict__ psi_mid,
                                                  const unsigned short* __restrict__ vpxf_hi,
                                                  const unsigned short* __restrict__ vpxf_lo,
                                                  float* __restrict__ M, int s0) {
  int z = blockIdx.z;
  int s = s0 + z;
  int lr0 = blockIdx.x * 64;       // gridDim.x = 64
  const float* W = psi_mid + (size_t)s * 4096 * 256;
  const unsigned short* Ahg = vpxf_hi + (size_t)(s + 1) * 65536;
  const unsigned short* Alg = vpxf_lo + (size_t)(s + 1) * 65536;
  __shared__ unsigned short Bh[2][2][4][64][8];   // [dbuf][kchunk][lr-tile][lane][8] = 16 KB
  __shared__ unsigned short Bl[2][2][4][64][8];   // 16 KB
  int t = threadIdx.x;
  int lane = t & 63, w = t >> 6;                  // w = 0..7
  int row = t >> 3, kg = t & 7;                   // row 0..63, kg 0..7 (8 k each)

  float4 sv0, sv1;                                // staged W regs

  #define LOADP(p) do {                                                        \
    const float* src = W + (size_t)(lr0 + row) * 256 + ((p) << 6) + kg * 8;    \
    sv0 = *(const float4*)src;                                                 \
    sv1 = *(const float4*)(src + 4);                                           \
  } while (0)

  #define WRITEP(d) do {                                                       \
    float xs[8] = {sv0.x, sv0.y, sv0.z, sv0.w, sv1.x, sv1.y, sv1.z, sv1.w};    \
    us8 hv, lv;                                                                \
    _Pragma("unroll")                                                          \
    for (int i = 0; i < 8; ++i) {                                              \
      unsigned short hb = f2bf(xs[i]);                                         \
      hv[i] = hb;                                                              \
      lv[i] = f2bf(xs[i] - bf2f(hb));                                          \
    }                                                                          \
    int ck = kg >> 2, nt = row >> 4, ln = ((kg & 3) << 4) | (row & 15);        \
    *(us8*)&Bh[d][ck][nt][ln][0] = hv;                                         \
    *(us8*)&Bl[d][ck][nt][ln][0] = lv;                                         \
  } while (0)

  f32x4 acc[2][4];
  #pragma unroll
  for (int i = 0; i < 2; ++i) {
    #pragma unroll
    for (int j = 0; j < 4; ++j) acc[i][j] = (f32x4){0.f, 0.f, 0.f, 0.f};
  }

  LOADP(0);
  WRITEP(0);
  __syncthreads();
  #pragma unroll
  for (int p = 0; p < 4; ++p) {
    int pb = p & 1;
    if (p < 3) LOADP(p + 1);       // issue next panel's loads early
    #pragma unroll
    for (int c = 0; c < 2; ++c) {
      int chunk = p * 2 + c;
      bf16x8 ah[2], al[2];
      #pragma unroll
      for (int mi = 0; mi < 2; ++mi) {
        int bt = w * 2 + mi;
        size_t fo = ((size_t)chunk * 16 + bt) * 512 + (size_t)lane * 8;
        ah[mi] = *(const bf16x8*)(Ahg + fo);
        al[mi] = *(const bf16x8*)(Alg + fo);
      }
      #pragma unroll
      for (int n = 0; n < 4; ++n) {
        bf16x8 bh = *(const bf16x8*)&Bh[pb][c][n][lane][0];
        bf16x8 bl = *(const bf16x8*)&Bl[pb][c][n][lane][0];
        #pragma unroll
        for (int mi = 0; mi < 2; ++mi) {
          acc[mi][n] = __builtin_amdgcn_mfma_f32_16x16x32_bf16(ah[mi], bh, acc[mi][n], 0, 0, 0);
          acc[mi][n] = __builtin_amdgcn_mfma_f32_16x16x32_bf16(al[mi], bh, acc[mi][n], 0, 0, 0);
          acc[mi][n] = __builtin_amdgcn_mfma_f32_16x16x32_bf16(ah[mi], bl, acc[mi][n], 0, 0, 0);
        }
      }
    }
    if (p < 3) WRITEP((p + 1) & 1);  // convert + LDS-write late
    __syncthreads();
  }
  #undef LOADP
  #undef WRITEP

  int rg = lane >> 4, cidx = lane & 15;
  #pragma unroll
  for (int mi = 0; mi < 2; ++mi) {
    int bbase = (w * 2 + mi) * 16 + rg * 4;
    #pragma unroll
    for (int n = 0; n < 4; ++n) {
      #pragma unroll
      for (int r = 0; r < 4; ++r) {
        M[((size_t)z * 256 + bbase + r) * 4096 + lr0 + n * 16 + cidx] = acc[mi][n][r];
      }
    }
  }
}

// ---------------------------------------------------------------------------
// K3: per-b psi chain through the chunk's M. 2-deep register prefetch.
__global__ __launch_bounds__(256) void k_psi_chain(const float* __restrict__ M,
                                                   const float* __restrict__ vpx,
                                                   const float* __restrict__ psi_first,
                                                   const float* __restrict__ psi_last,
                                                   float* __restrict__ vpsi,
                                                   float* __restrict__ psiv,
                                                   int nS, int isFirst, int isLast) {
  int b = blockIdx.x;
  int t = threadIdx.x;
  int r = t & 63, g = t >> 6;
  __shared__ float v[64];
  __shared__ float part[4][64];
  __shared__ float red[256];
  if (isFirst) {
    const float* u0 = vpx + (size_t)b * 256;
    float s0 = 0.f;
    for (int p = g * 64; p < g * 64 + 64; ++p) s0 += psi_first[r * 256 + p] * u0[p];
    part[g][r] = s0;
    __syncthreads();
    if (g == 0) v[r] = part[0][r] + part[1][r] + part[2][r] + part[3][r];
    __syncthreads();
  } else {
    if (g == 0) v[r] = vpsi[b * 64 + r];
    __syncthreads();
  }

  #define PLOAD(buf, sc) do {                                                  \
    const float* Mb = M + ((size_t)(sc) * 256 + b) * 4096 + r;                 \
    _Pragma("unroll")                                                          \
    for (int j = 0; j < 16; ++j) buf[j] = Mb[(size_t)(g * 16 + j) * 64];       \
  } while (0)

  #define PSTEP(buf) do {                                                      \
    float sum = 0.f;                                                           \
    _Pragma("unroll")                                                          \
    for (int j = 0; j < 16; ++j) sum += v[g * 16 + j] * buf[j];                \
    part[g][r] = sum;                                                          \
    __syncthreads();                                                           \
    if (g == 0) v[r] = part[0][r] + part[1][r] + part[2][r] + part[3][r];      \
    __syncthreads();                                                           \
  } while (0)

  if (nS > 0) {
    float bufA[16], bufB[16];
    PLOAD(bufA, 0);
    int sc = 0;
    while (true) {
      if (sc + 1 < nS) PLOAD(bufB, sc + 1);
      PSTEP(bufA);
      ++sc;
      if (sc >= nS) break;
      if (sc + 1 < nS) PLOAD(bufA, sc + 1);
      PSTEP(bufB);
      ++sc;
      if (sc >= nS) break;
    }
  }
  #undef PLOAD
  #undef PSTEP

  if (isLast) {
    float qv = 0.f;
    for (int l = 0; l < 64; ++l) qv += v[l] * psi_last[l * 256 + t];
    red[t] = qv * vpx[((size_t)63 * 256 + b) * 256 + t];
    __syncthreads();
    for (int off = 128; off > 0; off >>= 1) {
      if (t < off) red[t] += red[t + off];
      __syncthreads();
    }
    if (t == 0) psiv[b] = red[0];
  } else {
    if (g == 0) vpsi[b * 64 + r] = v[r];
  }
}

// ---------------------------------------------------------------------------
// phi chain body (batch-independent), runs in one 256-thread block.
__device__ __forceinline__ void phi_chain_body(const float* __restrict__ slices,
                                               const float* __restrict__ phi_first,
                                               const float* __restrict__ phi_last,
                                               float* __restrict__ phiv) {
  int t = threadIdx.x;
  int r = t & 63, g = t >> 6;
  __shared__ float u[64];
  __shared__ float part[4][64];
  __shared__ float red[64];
  if (t < 64) u[t] = phi_first[t * 64];      // e[0] one-hot at p=0
  __syncthreads();
  for (int i = 0; i < 62; ++i) {
    float sum = 0.f;
    #pragma unroll
    for (int j = 0; j < 16; ++j) {
      int l = g * 16 + j;
      sum += u[l] * slices[(size_t)i * 4096 + l * 64 + r];
    }
    part[g][r] = sum;
    __syncthreads();
    if (g == 0) u[r] = part[0][r] + part[1][r] + part[2][r] + part[3][r];
    __syncthreads();
  }
  if (t < 64) red[t] = u[t] * phi_last[t * 64 + 63];
  __syncthreads();
  if (t == 0) {
    float s = 0.f;
    for (int l = 0; l < 64; ++l) s += red[l];
    *phiv = s;
  }
}

__global__ __launch_bounds__(256) void k_phi_chain(const float* __restrict__ slices,
                                                   const float* __restrict__ phi_first,
                                                   const float* __restrict__ phi_last,
                                                   float* __restrict__ phiv) {
  phi_chain_body(slices, phi_first, phi_last, phiv);
}

// ---------------------------------------------------------------------------
// K4a: Tc[z][b][r*32+l] = sum_c chi_mid[s0+z][l][r][c] * vch[s0+z+1][b][c]
// Fused: block x == phiBlock (y==0) runs the phi chain instead.
__global__ __launch_bounds__(256) void k_chi_gemm(const float* __restrict__ chi_mid,
                                                  const float* __restrict__ vch,
                                                  float* __restrict__ Tc, int s0,
                                                  int phiBlock,
                                                  const float* __restrict__ slices,
                                                  const float* __restrict__ phi_first,
                                                  const float* __restrict__ phi_last,
                                                  float* __restrict__ phiv) {
  if ((int)blockIdx.x == phiBlock) {
    if (blockIdx.y == 0) phi_chain_body(slices, phi_first, phi_last, phiv);
    return;
  }
  int z = blockIdx.x;
  int s = s0 + z;
  int b0 = blockIdx.y * 32;
  int t = threadIdx.x;
  __shared__ float uv[32][16];
  if (t < 128) {
    int idx = t * 4;
    int b = idx >> 4, c = idx & 15;
    *(float4*)&uv[b][c] = *(const float4*)(vch + ((size_t)(s + 1) * 256 + b0 + b) * 16 + c);
  }
  __syncthreads();
  #pragma unroll
  for (int k = 0; k < 4; ++k) {
    int idx = t + k * 256;           // output index = r*32 + l
    int r = idx >> 5, l = idx & 31;
    const float* Wp = chi_mid + ((size_t)s * 1024 + l * 32 + r) * 16;
    float4 w0 = *(const float4*)(Wp);
    float4 w1 = *(const float4*)(Wp + 4);
    float4 w2 = *(const float4*)(Wp + 8);
    float4 w3 = *(const float4*)(Wp + 12);
    for (int b = 0; b < 32; ++b) {
      const float* u = uv[b];
      float d = w0.x * u[0] + w0.y * u[1] + w0.z * u[2] + w0.w * u[3]
              + w1.x * u[4] + w1.y * u[5] + w1.z * u[6] + w1.w * u[7]
              + w2.x * u[8] + w2.y * u[9] + w2.z * u[10] + w2.w * u[11]
              + w3.x * u[12] + w3.y * u[13] + w3.z * u[14] + w3.w * u[15];
      Tc[((size_t)z * 256 + b0 + b) * 1024 + idx] = d;
    }
  }
}

// ---------------------------------------------------------------------------
// K4b: per-b chi chain, 1 wave per b, 2-deep register prefetch.
__global__ __launch_bounds__(64) void k_chi_chain(const float* __restrict__ Tc,
                                                  const float* __restrict__ chi_first,
                                                  const float* __restrict__ chi_last,
                                                  const float* __restrict__ vch,
                                                  const float* __restrict__ psiv,
                                                  const float* __restrict__ phiv,
                                                  float* __restrict__ vchi,
                                                  float* __restrict__ out,
                                                  int nS, int isFirst, int isLast) {
  int b = blockIdx.x;
  int lane = threadIdx.x;
  int r = lane & 31, h = lane >> 5;
  __shared__ float v[32];
  if (isFirst) {
    if (h == 0) {
      const float* u0 = vch + (size_t)b * 16;   // site 0
      const float* cf = chi_first + r * 16;
      float s0 = 0.f;
      #pragma unroll
      for (int c = 0; c < 16; ++c) s0 += cf[c] * u0[c];
      v[r] = s0;
    }
  } else {
    if (h == 0) v[r] = vchi[b * 32 + r];
  }
  __syncthreads();

  #define CLOAD(buf, sc) do {                                                  \
    const float* Mb = Tc + ((size_t)(sc) * 256 + b) * 1024 + r * 32 + h * 16;  \
    *(float4*)&buf[0]  = *(const float4*)(Mb);                                 \
    *(float4*)&buf[4]  = *(const float4*)(Mb + 4);                             \
    *(float4*)&buf[8]  = *(const float4*)(Mb + 8);                             \
    *(float4*)&buf[12] = *(const float4*)(Mb + 12);                            \
  } while (0)

  #define CSTEP(buf) do {                                                      \
    const float* vv = &v[h * 16];                                              \
    float sum = 0.f;                                                           \
    _Pragma("unroll")                                                          \
    for (int j = 0; j < 16; ++j) sum += buf[j] * vv[j];                        \
    sum += __shfl_xor(sum, 32);                                                \
    __syncthreads();                                                           \
    if (h == 0) v[r] = sum;                                                    \
    __syncthreads();                                                           \
  } while (0)

  if (nS > 0) {
    float bufA[16], bufB[16];
    CLOAD(bufA, 0);
    int sc = 0;
    while (true) {
      if (sc + 1 < nS) CLOAD(bufB, sc + 1);
      CSTEP(bufA);
      ++sc;
      if (sc >= nS) break;
      if (sc + 1 < nS) CLOAD(bufA, sc + 1);
      CSTEP(bufB);
      ++sc;
      if (sc >= nS) break;
    }
  }
  #undef CLOAD
  #undef CSTEP

  if (isLast) {
    const float* u63 = vch + ((size_t)63 * 256 + b) * 16;
    float uc[16];
    #pragma unroll
    for (int c = 0; c < 16; ++c) uc[c] = u63[c];
    float scale = 0.5f * psiv[b] * phiv[0];
    for (int o = 0; o < 10; ++o) {
      const float* cl = chi_last + r * 16 * 10 + o;
      float w = 0.f;
      #pragma unroll
      for (int c = 0; c < 16; ++c) w += cl[c * 10] * uc[c];
      float p = v[r] * w;                       // duplicated across halves
      #pragma unroll
      for (int m = 32; m > 0; m >>= 1) p += __shfl_xor(p, m);
      if (lane == 0) out[b * 10 + o] = p * scale;
    }
  } else {
    if (h == 0) vchi[b * 32 + r] = v[r];
  }
}

// ---------------------------------------------------------------------------
// Fallback fused chi (tiny workspace): serial chain + combine.
__global__ __launch_bounds__(256) void k_chi_fused(const float* __restrict__ chi_first,
                                                   const float* __restrict__ chi_mid,
                                                   const float* __restrict__ chi_last,
                                                   const float* __restrict__ vch,
                                                   const float* __restrict__ psiv,
                                                   const float* __restrict__ phiv,
                                                   float* __restrict__ out) {
  int t = threadIdx.x;
  int bl = t >> 6, lg = (t >> 5) & 1, r = t & 31;
  int b = blockIdx.x * 4 + bl;
  __shared__ float v[4][32];
  __shared__ float part[4][2][32];
  if (lg == 0) {
    const float* u0 = vch + (size_t)b * 16;
    float s0 = 0.f;
    #pragma unroll
    for (int c = 0; c < 16; ++c) s0 += chi_first[r * 16 + c] * u0[c];
    v[bl][r] = s0;
  }
  __syncthreads();
  for (int s = 0; s < 62; ++s) {
    const float* u = vch + ((size_t)(s + 1) * 256 + b) * 16;
    float uc[16];
    #pragma unroll
    for (int c = 0; c < 16; ++c) uc[c] = u[c];
    const float* W = chi_mid + (size_t)s * 32 * 32 * 16;
    float sum = 0.f;
    #pragma unroll
    for (int j = 0; j < 16; ++j) {
      int l = lg * 16 + j;
      const float* Wl = W + ((size_t)l * 32 + r) * 16;
      float tt = 0.f;
      #pragma unroll
      for (int c = 0; c < 16; ++c) tt += Wl[c] * uc[c];
      sum += v[bl][l] * tt;
    }
    part[bl][lg][r] = sum;
    __syncthreads();
    if (lg == 0) v[bl][r] = part[bl][0][r] + part[bl][1][r];
    __syncthreads();
  }
  const float* u63 = vch + ((size_t)63 * 256 + b) * 16;
  float uc[16];
  #pragma unroll
  for (int c = 0; c < 16; ++c) uc[c] = u63[c];
  if (r < 10) {
    float acc = 0.f;
    #pragma unroll
    for (int j = 0; j < 16; ++j) {
      int l = lg * 16 + j;
      const float* cl = chi_last + (size_t)l * 16 * 10;
      float tt = 0.f;
      #pragma unroll
      for (int c = 0; c < 16; ++c) tt += cl[c * 10 + r] * uc[c];
      acc += v[bl][l] * tt;
    }
    part[bl][lg][r] = acc;
  }
  __syncthreads();
  if (lg == 0 && r < 10)
    out[b * 10 + r] = (part[bl][0][r] + part[bl][1][r]) * psiv[b] * phiv[0];
}

// ---------------------------------------------------------------------------
// Fallback (tiny workspace): per-b full psi chain from x directly.
__global__ __launch_bounds__(256) void k_psi_direct(const float* __restrict__ x,
                                                    const float* __restrict__ psi_mid,
                                                    const float* __restrict__ psi_first,
                                                    const float* __restrict__ psi_last,
                                                    float* __restrict__ psiv) {
  int b = blockIdx.x;
  int t = threadIdx.x;
  int r = t & 63, g = t >> 6;
  __shared__ float u[256];
  __shared__ float v[64];
  __shared__ float part[4][64];
  __shared__ float red[256];
  const float* xb = x + ((size_t)b << 18);
  {
    const float* rw = xb + (size_t)0 * 4096 + t * 16;
    float sm = 0.f;
    #pragma unroll
    for (int c = 0; c < 16; ++c) sm += rw[c];
    u[t] = sm * (1.0f / 16.0f);
  }
  __syncthreads();
  {
    float s0 = 0.f;
    for (int p = g * 64; p < g * 64 + 64; ++p) s0 += psi_first[r * 256 + p] * u[p];
    part[g][r] = s0;
    __syncthreads();
    if (g == 0) v[r] = part[0][r] + part[1][r] + part[2][r] + part[3][r];
  }
  __syncthreads();
  for (int s = 0; s < 62; ++s) {
    __syncthreads();
    {
      const float* rw = xb + (size_t)(s + 1) * 4096 + t * 16;
      float sm = 0.f;
      #pragma unroll
      for (int c = 0; c < 16; ++c) sm += rw[c];
      u[t] = sm * (1.0f / 16.0f);
    }
    __syncthreads();
    const float* W = psi_mid + (size_t)s * 4096 * 256;
    float sum = 0.f;
    for (int l = 0; l < 64; ++l) {
      const float* Wl = W + ((size_t)(l * 64 + r)) * 256 + g * 64;
      float tt = 0.f;
      #pragma unroll 8
      for (int k = 0; k < 64; ++k) tt += Wl[k] * u[g * 64 + k];
      sum += v[l] * tt;
    }
    part[g][r] = sum;
    __syncthreads();
    if (g == 0) v[r] = part[0][r] + part[1][r] + part[2][r] + part[3][r];
    __syncthreads();
  }
  __syncthreads();
  {
    const float* rw = xb + (size_t)63 * 4096 + t * 16;
    float sm = 0.f;
    #pragma unroll
    for (int c = 0; c < 16; ++c) sm += rw[c];
    u[t] = sm * (1.0f / 16.0f);
  }
  __syncthreads();
  float qv = 0.f;
  for (int l = 0; l < 64; ++l) qv += v[l] * psi_last[l * 256 + t];
  red[t] = qv * u[t];
  __syncthreads();
  for (int off = 128; off > 0; off >>= 1) {
    if (t < off) red[t] += red[t + off];
    __syncthreads();
  }
  if (t == 0) psiv[b] = red[0];
}

// ---------------------------------------------------------------------------
extern "C" void kernel_launch(void* const* d_in, const int* in_sizes, int n_in,
                              void* d_out, int out_size, void* d_ws, size_t ws_size,
                              hipStream_t stream) {
  const float* x         = (const float*)d_in[0];
  const float* chi_first = (const float*)d_in[1];
  const float* chi_mid   = (const float*)d_in[2];
  const float* chi_last  = (const float*)d_in[3];
  const float* psi_first = (const float*)d_in[4];
  const float* psi_mid   = (const float*)d_in[5];
  const float* psi_last  = (const float*)d_in[6];
  const float* phi_first = (const float*)d_in[7];
  const float* phi_mid   = (const float*)d_in[8];
  const float* phi_last  = (const float*)d_in[9];
  float* out = (float*)d_out;
  float* ws  = (float*)d_ws;

  size_t wsf = ws_size / 4;
  size_t off = 0;
  float* vch    = ws + off; off += (size_t)64 * 256 * 16;     // 262144
  float* psiv   = ws + off; off += 256;
  float* phisl  = ws + off; off += (size_t)62 * 64 * 64;      // 253952
  float* phiv   = ws + off; off += 16;
  float* vpsi   = ws + off; off += (size_t)64 * 256;          // 16384
  float* vchi   = ws + off; off += (size_t)32 * 256;          // 8192
  float* vpx    = ws + off; off += (size_t)64 * 256 * 256;    // 4194304
  unsigned short* vpxf_hi = (unsigned short*)(ws + off); off += (size_t)64 * 65536 / 2;
  unsigned short* vpxf_lo = (unsigned short*)(ws + off); off += (size_t)64 * 65536 / 2;
  float* Mbuf   = ws + off;                                   // shared by psi-M and chi-Tc
  size_t mfloats = (wsf > off) ? (wsf - off) : 0;
  int C = (int)(mfloats / ((size_t)256 * 4096));              // psi sites per chunk
  if (C > 16) C = 16;                                         // keep M chunk LLC-resident
  int Cc = (int)(mfloats / ((size_t)256 * 1024));             // chi sites per chunk
  if (Cc > 62) Cc = 62;
  bool pathA = (C >= 1);

  if (pathA) {
    k_reduce_x<<<16384 + 62, 256, 0, stream>>>(x, vch, vpx, vpxf_hi, vpxf_lo,
                                               phi_mid, phisl);
    // psi: chunked GEMM + chain (Mbuf holds C sites of M)
    int done = 0;
    while (done < 62) {
      int c = imin(C, 62 - done);
      k_psi_gemm<<<dim3(64, 1, c), 512, 0, stream>>>(psi_mid, vpxf_hi, vpxf_lo, Mbuf, done);
      k_psi_chain<<<256, 256, 0, stream>>>(Mbuf, vpx, psi_first, psi_last,
                                           vpsi, psiv, c, (done == 0) ? 1 : 0,
                                           (done + c == 62) ? 1 : 0);
      done += c;
    }
    // chi: chunked contraction (phi chain fused into first chunk's dispatch)
    done = 0;
    while (done < 62) {
      int c = imin(Cc, 62 - done);
      int phiBlk = (done == 0) ? c : -1;
      int gx = (done == 0) ? (c + 1) : c;
      k_chi_gemm<<<dim3(gx, 8), 256, 0, stream>>>(chi_mid, vch, Mbuf, done, phiBlk,
                                                  phisl, phi_first, phi_last, phiv);
      k_chi_chain<<<256, 64, 0, stream>>>(Mbuf, chi_first, chi_last, vch,
                                          psiv, phiv, vchi, out, c,
                                          (done == 0) ? 1 : 0,
                                          (done + c == 62) ? 1 : 0);
      done += c;
    }
  } else {
    k_reduce_x<<<16384 + 62, 256, 0, stream>>>(x, vch, nullptr, nullptr, nullptr,
                                               phi_mid, phisl);
    k_psi_direct<<<256, 256, 0, stream>>>(x, psi_mid, psi_first, psi_last, psiv);
    k_phi_chain<<<1, 256, 0, stream>>>(phisl, phi_first, phi_last, phiv);
    k_chi_fused<<<64, 256, 0, stream>>>(chi_first, chi_mid, chi_last, vch, psiv, phiv, out);
  }
}

// Round 7
// 385.192 us; speedup vs baseline: 1.0246x; 1.0246x over previous
//
#include <hip/hip_runtime.h>

// dims: L=64, CH=16, PIX=256, PAT=64, RC=32, BD=64, OUT=10, B=256
// inputs: 0=x(256,64,256,16) 1=chi_first(32,16) 2=chi_mid(62,32,32,16)
// 3=chi_last(32,16,10) 4=psi_first(64,256) 5=psi_mid(62,64,64,256)
// 6=psi_last(64,256) 7=phi_first(64,64) 8=phi_mid(62,64,64,64) 9=phi_last(64,64)

static inline int imin(int a, int b) { return a < b ? a : b; }

typedef __attribute__((ext_vector_type(8))) short bf16x8;          // 8 bf16 (4 VGPR)
typedef __attribute__((ext_vector_type(8))) unsigned short us8;
typedef __attribute__((ext_vector_type(4))) float f32x4;

__device__ __forceinline__ unsigned short f2bf(float v) {
  union { float f; unsigned int u; } c; c.f = v;
  unsigned int u = c.u;
  unsigned int r = (u + 0x7fffu + ((u >> 16) & 1u)) >> 16;  // RTN-even
  return (unsigned short)r;
}
__device__ __forceinline__ float bf2f(unsigned short h) {
  union { unsigned int u; float f; } c; c.u = ((unsigned int)h) << 16;
  return c.f;
}

// ---------------------------------------------------------------------------
// K1: vpx means + bf16 hi/lo fragment emit. Fused: blocks >= 16384 do the
// phi slice gather (slices[i][l*64+r] = phi_mid[i][l][r][i+1]).
__global__ __launch_bounds__(256) void k_reduce_x(const float* __restrict__ x,
                                                  float* __restrict__ vch,
                                                  float* __restrict__ vpx,
                                                  unsigned short* __restrict__ vpxf_hi,
                                                  unsigned short* __restrict__ vpxf_lo,
                                                  const float* __restrict__ phi_mid,
                                                  float* __restrict__ slices) {
  if (blockIdx.x >= 16384) {                 // phi gather block
    int i = blockIdx.x - 16384;              // 0..61
    int t = threadIdx.x;
    #pragma unroll
    for (int k = 0; k < 16; ++k) {
      int idx = t + k * 256;                 // l*64 + r
      slices[(size_t)i * 4096 + idx] = phi_mid[((size_t)i * 4096 + idx) * 64 + (i + 1)];
    }
    return;
  }
  int bp = blockIdx.x;             // b*64 + s
  int b = bp >> 6, s = bp & 63;
  int q = threadIdx.x;             // = p
  const float* row = x + ((size_t)bp << 12) + q * 16;
  float4 r0 = *(const float4*)(row);
  float4 r1 = *(const float4*)(row + 4);
  float4 r2 = *(const float4*)(row + 8);
  float4 r3 = *(const float4*)(row + 12);
  float csum = r0.x + r0.y + r0.z + r0.w + r1.x + r1.y + r1.z + r1.w
             + r2.x + r2.y + r2.z + r2.w + r3.x + r3.y + r3.z + r3.w;
  float val = csum * (1.0f / 16.0f);
  if (vpx && (s == 0 || s == 63)) vpx[((size_t)s * 256 + b) * 256 + q] = val;
  if (vpxf_hi && s >= 1 && s <= 62) {
    unsigned short hb = f2bf(val);
    unsigned short lb = f2bf(val - bf2f(hb));
    size_t fa = (size_t)s * 65536
              + (((size_t)(q >> 5) * 16 + (b >> 4)) * 64 + (((q >> 3) & 3) * 16 + (b & 15))) * 8
              + (q & 7);
    vpxf_hi[fa] = hb;
    vpxf_lo[fa] = lb;
  }

  __shared__ float sc[256][20];
  *(float4*)&sc[q][0]  = r0;
  *(float4*)&sc[q][4]  = r1;
  *(float4*)&sc[q][8]  = r2;
  *(float4*)&sc[q][12] = r3;
  __syncthreads();
  int c = q & 15, g = q >> 4;
  float ps = 0.f;
  #pragma unroll
  for (int k = 0; k < 16; ++k) ps += sc[g * 16 + k][c];
  __shared__ float p2[16][17];
  p2[g][c] = ps;
  __syncthreads();
  if (q < 16) {
    float s2 = 0.f;
    #pragma unroll
    for (int k = 0; k < 16; ++k) s2 += p2[k][q];
    vch[((size_t)s * 256 + b) * 16 + q] = s2 * (1.0f / 256.0f);
  }
}

// ---------------------------------------------------------------------------
// K2 (MFMA): M[z][b][lr] = sum_p W[s][lr][p] * vpx[s+1][b][p], hi/lo bf16.
// 512 threads / 8 waves; wave w owns b-tiles w*2+{0,1} (32 b) x 64 lr.
// A-fragment RING prefetch: chunk c+1's global A loads issue before chunk c's
// 24 MFMAs (all ring/acc indices compile-time via full unroll). Chunk 0's A
// issues before W staging so it flies under the convert+LDS-write.
__global__ __launch_bounds__(512) void k_psi_gemm(const float* __restrict__ psi_mid,
                                                  const unsigned short* __restrict__ vpxf_hi,
                                                  const unsigned short* __restrict__ vpxf_lo,
                                                  float* __restrict__ M, int s0) {
  int z = blockIdx.z;
  int s = s0 + z;
  int lr0 = blockIdx.x * 64;       // gridDim.x = 64
  const float* W = psi_mid + (size_t)s * 4096 * 256;
  const unsigned short* Ahg = vpxf_hi + (size_t)(s + 1) * 65536;
  const unsigned short* Alg = vpxf_lo + (size_t)(s + 1) * 65536;
  __shared__ unsigned short Bh[2][2][4][64][8];   // [dbuf][kchunk][lr-tile][lane][8] = 16 KB
  __shared__ unsigned short Bl[2][2][4][64][8];   // 16 KB
  int t = threadIdx.x;
  int lane = t & 63, w = t >> 6;                  // w = 0..7
  int row = t >> 3, kg = t & 7;                   // row 0..63, kg 0..7 (8 k each)

  float4 sv0, sv1;                                // staged W regs

  #define LOADP(p) do {                                                        \
    const float* src = W + (size_t)(lr0 + row) * 256 + ((p) << 6) + kg * 8;    \
    sv0 = *(const float4*)src;                                                 \
    sv1 = *(const float4*)(src + 4);                                           \
  } while (0)

  #define WRITEP(d) do {                                                       \
    float xs[8] = {sv0.x, sv0.y, sv0.z, sv0.w, sv1.x, sv1.y, sv1.z, sv1.w};    \
    us8 hv, lv;                                                                \
    _Pragma("unroll")                                                          \
    for (int i = 0; i < 8; ++i) {                                              \
      unsigned short hb = f2bf(xs[i]);                                         \
      hv[i] = hb;                                                              \
      lv[i] = f2bf(xs[i] - bf2f(hb));                                          \
    }                                                                          \
    int ck = kg >> 2, nt = row >> 4, ln = ((kg & 3) << 4) | (row & 15);        \
    *(us8*)&Bh[d][ck][nt][ln][0] = hv;                                         \
    *(us8*)&Bl[d][ck][nt][ln][0] = lv;                                         \
  } while (0)

  #define LOADA(slot, chunk) do {                                              \
    _Pragma("unroll")                                                          \
    for (int mi = 0; mi < 2; ++mi) {                                           \
      size_t fo = ((size_t)(chunk) * 16 + (w * 2 + mi)) * 512 + (size_t)lane * 8; \
      Ah[slot][mi] = *(const bf16x8*)(Ahg + fo);                               \
      Al[slot][mi] = *(const bf16x8*)(Alg + fo);                               \
    }                                                                          \
  } while (0)

  f32x4 acc[2][4];
  #pragma unroll
  for (int i = 0; i < 2; ++i) {
    #pragma unroll
    for (int j = 0; j < 4; ++j) acc[i][j] = (f32x4){0.f, 0.f, 0.f, 0.f};
  }
  bf16x8 Ah[2][2], Al[2][2];       // [ring slot][mi] -- all indices static

  LOADA(0, 0);                     // chunk 0 A in flight during staging
  LOADP(0);
  WRITEP(0);
  __syncthreads();
  #pragma unroll
  for (int p = 0; p < 4; ++p) {
    if (p < 3) LOADP(p + 1);       // issue next W panel's loads early
    #pragma unroll
    for (int c = 0; c < 2; ++c) {
      const int chunk = p * 2 + c;           // compile-time after unroll
      const int cur = chunk & 1, nxt = (chunk + 1) & 1;
      if (chunk < 7) LOADA(nxt, chunk + 1);  // prefetch next chunk's A
      #pragma unroll
      for (int n = 0; n < 4; ++n) {
        bf16x8 bh = *(const bf16x8*)&Bh[p & 1][c][n][lane][0];
        bf16x8 bl = *(const bf16x8*)&Bl[p & 1][c][n][lane][0];
        #pragma unroll
        for (int mi = 0; mi < 2; ++mi) {
          acc[mi][n] = __builtin_amdgcn_mfma_f32_16x16x32_bf16(Ah[cur][mi], bh, acc[mi][n], 0, 0, 0);
          acc[mi][n] = __builtin_amdgcn_mfma_f32_16x16x32_bf16(Al[cur][mi], bh, acc[mi][n], 0, 0, 0);
          acc[mi][n] = __builtin_amdgcn_mfma_f32_16x16x32_bf16(Ah[cur][mi], bl, acc[mi][n], 0, 0, 0);
        }
      }
    }
    if (p < 3) WRITEP((p + 1) & 1);  // convert + LDS-write late
    __syncthreads();
  }
  #undef LOADP
  #undef WRITEP
  #undef LOADA

  int rg = lane >> 4, cidx = lane & 15;
  #pragma unroll
  for (int mi = 0; mi < 2; ++mi) {
    int bbase = (w * 2 + mi) * 16 + rg * 4;
    #pragma unroll
    for (int n = 0; n < 4; ++n) {
      #pragma unroll
      for (int r = 0; r < 4; ++r) {
        M[((size_t)z * 256 + bbase + r) * 4096 + lr0 + n * 16 + cidx] = acc[mi][n][r];
      }
    }
  }
}

// ---------------------------------------------------------------------------
// K3: per-b psi chain through the chunk's M. 2-deep register prefetch.
__global__ __launch_bounds__(256) void k_psi_chain(const float* __restrict__ M,
                                                   const float* __restrict__ vpx,
                                                   const float* __restrict__ psi_first,
                                                   const float* __restrict__ psi_last,
                                                   float* __restrict__ vpsi,
                                                   float* __restrict__ psiv,
                                                   int nS, int isFirst, int isLast) {
  int b = blockIdx.x;
  int t = threadIdx.x;
  int r = t & 63, g = t >> 6;
  __shared__ float v[64];
  __shared__ float part[4][64];
  __shared__ float red[256];
  if (isFirst) {
    const float* u0 = vpx + (size_t)b * 256;
    float s0 = 0.f;
    for (int p = g * 64; p < g * 64 + 64; ++p) s0 += psi_first[r * 256 + p] * u0[p];
    part[g][r] = s0;
    __syncthreads();
    if (g == 0) v[r] = part[0][r] + part[1][r] + part[2][r] + part[3][r];
    __syncthreads();
  } else {
    if (g == 0) v[r] = vpsi[b * 64 + r];
    __syncthreads();
  }

  #define PLOAD(buf, sc) do {                                                  \
    const float* Mb = M + ((size_t)(sc) * 256 + b) * 4096 + r;                 \
    _Pragma("unroll")                                                          \
    for (int j = 0; j < 16; ++j) buf[j] = Mb[(size_t)(g * 16 + j) * 64];       \
  } while (0)

  #define PSTEP(buf) do {                                                      \
    float sum = 0.f;                                                           \
    _Pragma("unroll")                                                          \
    for (int j = 0; j < 16; ++j) sum += v[g * 16 + j] * buf[j];                \
    part[g][r] = sum;                                                          \
    __syncthreads();                                                           \
    if (g == 0) v[r] = part[0][r] + part[1][r] + part[2][r] + part[3][r];      \
    __syncthreads();                                                           \
  } while (0)

  if (nS > 0) {
    float bufA[16], bufB[16];
    PLOAD(bufA, 0);
    int sc = 0;
    while (true) {
      if (sc + 1 < nS) PLOAD(bufB, sc + 1);
      PSTEP(bufA);
      ++sc;
      if (sc >= nS) break;
      if (sc + 1 < nS) PLOAD(bufA, sc + 1);
      PSTEP(bufB);
      ++sc;
      if (sc >= nS) break;
    }
  }
  #undef PLOAD
  #undef PSTEP

  if (isLast) {
    float qv = 0.f;
    for (int l = 0; l < 64; ++l) qv += v[l] * psi_last[l * 256 + t];
    red[t] = qv * vpx[((size_t)63 * 256 + b) * 256 + t];
    __syncthreads();
    for (int off = 128; off > 0; off >>= 1) {
      if (t < off) red[t] += red[t + off];
      __syncthreads();
    }
    if (t == 0) psiv[b] = red[0];
  } else {
    if (g == 0) vpsi[b * 64 + r] = v[r];
  }
}

// ---------------------------------------------------------------------------
// phi chain body (batch-independent), runs in one 256-thread block.
__device__ __forceinline__ void phi_chain_body(const float* __restrict__ slices,
                                               const float* __restrict__ phi_first,
                                               const float* __restrict__ phi_last,
                                               float* __restrict__ phiv) {
  int t = threadIdx.x;
  int r = t & 63, g = t >> 6;
  __shared__ float u[64];
  __shared__ float part[4][64];
  __shared__ float red[64];
  if (t < 64) u[t] = phi_first[t * 64];      // e[0] one-hot at p=0
  __syncthreads();
  for (int i = 0; i < 62; ++i) {
    float sum = 0.f;
    #pragma unroll
    for (int j = 0; j < 16; ++j) {
      int l = g * 16 + j;
      sum += u[l] * slices[(size_t)i * 4096 + l * 64 + r];
    }
    part[g][r] = sum;
    __syncthreads();
    if (g == 0) u[r] = part[0][r] + part[1][r] + part[2][r] + part[3][r];
    __syncthreads();
  }
  if (t < 64) red[t] = u[t] * phi_last[t * 64 + 63];
  __syncthreads();
  if (t == 0) {
    float s = 0.f;
    for (int l = 0; l < 64; ++l) s += red[l];
    *phiv = s;
  }
}

__global__ __launch_bounds__(256) void k_phi_chain(const float* __restrict__ slices,
                                                   const float* __restrict__ phi_first,
                                                   const float* __restrict__ phi_last,
                                                   float* __restrict__ phiv) {
  phi_chain_body(slices, phi_first, phi_last, phiv);
}

// ---------------------------------------------------------------------------
// K4a: Tc[z][b][r*32+l] = sum_c chi_mid[s0+z][l][r][c] * vch[s0+z+1][b][c]
// Fused: block x == phiBlock (y==0) runs the phi chain instead.
__global__ __launch_bounds__(256) void k_chi_gemm(const float* __restrict__ chi_mid,
                                                  const float* __restrict__ vch,
                                                  float* __restrict__ Tc, int s0,
                                                  int phiBlock,
                                                  const float* __restrict__ slices,
                                                  const float* __restrict__ phi_first,
                                                  const float* __restrict__ phi_last,
                                                  float* __restrict__ phiv) {
  if ((int)blockIdx.x == phiBlock) {
    if (blockIdx.y == 0) phi_chain_body(slices, phi_first, phi_last, phiv);
    return;
  }
  int z = blockIdx.x;
  int s = s0 + z;
  int b0 = blockIdx.y * 32;
  int t = threadIdx.x;
  __shared__ float uv[32][16];
  if (t < 128) {
    int idx = t * 4;
    int b = idx >> 4, c = idx & 15;
    *(float4*)&uv[b][c] = *(const float4*)(vch + ((size_t)(s + 1) * 256 + b0 + b) * 16 + c);
  }
  __syncthreads();
  #pragma unroll
  for (int k = 0; k < 4; ++k) {
    int idx = t + k * 256;           // output index = r*32 + l
    int r = idx >> 5, l = idx & 31;
    const float* Wp = chi_mid + ((size_t)s * 1024 + l * 32 + r) * 16;
    float4 w0 = *(const float4*)(Wp);
    float4 w1 = *(const float4*)(Wp + 4);
    float4 w2 = *(const float4*)(Wp + 8);
    float4 w3 = *(const float4*)(Wp + 12);
    for (int b = 0; b < 32; ++b) {
      const float* u = uv[b];
      float d = w0.x * u[0] + w0.y * u[1] + w0.z * u[2] + w0.w * u[3]
              + w1.x * u[4] + w1.y * u[5] + w1.z * u[6] + w1.w * u[7]
              + w2.x * u[8] + w2.y * u[9] + w2.z * u[10] + w2.w * u[11]
              + w3.x * u[12] + w3.y * u[13] + w3.z * u[14] + w3.w * u[15];
      Tc[((size_t)z * 256 + b0 + b) * 1024 + idx] = d;
    }
  }
}

// ---------------------------------------------------------------------------
// K4b: per-b chi chain, 1 wave per b, 2-deep register prefetch.
__global__ __launch_bounds__(64) void k_chi_chain(const float* __restrict__ Tc,
                                                  const float* __restrict__ chi_first,
                                                  const float* __restrict__ chi_last,
                                                  const float* __restrict__ vch,
                                                  const float* __restrict__ psiv,
                                                  const float* __restrict__ phiv,
                                                  float* __restrict__ vchi,
                                                  float* __restrict__ out,
                                                  int nS, int isFirst, int isLast) {
  int b = blockIdx.x;
  int lane = threadIdx.x;
  int r = lane & 31, h = lane >> 5;
  __shared__ float v[32];
  if (isFirst) {
    if (h == 0) {
      const float* u0 = vch + (size_t)b * 16;   // site 0
      const float* cf = chi_first + r * 16;
      float s0 = 0.f;
      #pragma unroll
      for (int c = 0; c < 16; ++c) s0 += cf[c] * u0[c];
      v[r] = s0;
    }
  } else {
    if (h == 0) v[r] = vchi[b * 32 + r];
  }
  __syncthreads();

  #define CLOAD(buf, sc) do {                                                  \
    const float* Mb = Tc + ((size_t)(sc) * 256 + b) * 1024 + r * 32 + h * 16;  \
    *(float4*)&buf[0]  = *(const float4*)(Mb);                                 \
    *(float4*)&buf[4]  = *(const float4*)(Mb + 4);                             \
    *(float4*)&buf[8]  = *(const float4*)(Mb + 8);                             \
    *(float4*)&buf[12] = *(const float4*)(Mb + 12);                            \
  } while (0)

  #define CSTEP(buf) do {                                                      \
    const float* vv = &v[h * 16];                                              \
    float sum = 0.f;                                                           \
    _Pragma("unroll")                                                          \
    for (int j = 0; j < 16; ++j) sum += buf[j] * vv[j];                        \
    sum += __shfl_xor(sum, 32);                                                \
    __syncthreads();                                                           \
    if (h == 0) v[r] = sum;                                                    \
    __syncthreads();                                                           \
  } while (0)

  if (nS > 0) {
    float bufA[16], bufB[16];
    CLOAD(bufA, 0);
    int sc = 0;
    while (true) {
      if (sc + 1 < nS) CLOAD(bufB, sc + 1);
      CSTEP(bufA);
      ++sc;
      if (sc >= nS) break;
      if (sc + 1 < nS) CLOAD(bufA, sc + 1);
      CSTEP(bufB);
      ++sc;
      if (sc >= nS) break;
    }
  }
  #undef CLOAD
  #undef CSTEP

  if (isLast) {
    const float* u63 = vch + ((size_t)63 * 256 + b) * 16;
    float uc[16];
    #pragma unroll
    for (int c = 0; c < 16; ++c) uc[c] = u63[c];
    float scale = 0.5f * psiv[b] * phiv[0];
    for (int o = 0; o < 10; ++o) {
      const float* cl = chi_last + r * 16 * 10 + o;
      float w = 0.f;
      #pragma unroll
      for (int c = 0; c < 16; ++c) w += cl[c * 10] * uc[c];
      float p = v[r] * w;                       // duplicated across halves
      #pragma unroll
      for (int m = 32; m > 0; m >>= 1) p += __shfl_xor(p, m);
      if (lane == 0) out[b * 10 + o] = p * scale;
    }
  } else {
    if (h == 0) vchi[b * 32 + r] = v[r];
  }
}

// ---------------------------------------------------------------------------
// Fallback fused chi (tiny workspace): serial chain + combine.
__global__ __launch_bounds__(256) void k_chi_fused(const float* __restrict__ chi_first,
                                                   const float* __restrict__ chi_mid,
                                                   const float* __restrict__ chi_last,
                                                   const float* __restrict__ vch,
                                                   const float* __restrict__ psiv,
                                                   const float* __restrict__ phiv,
                                                   float* __restrict__ out) {
  int t = threadIdx.x;
  int bl = t >> 6, lg = (t >> 5) & 1, r = t & 31;
  int b = blockIdx.x * 4 + bl;
  __shared__ float v[4][32];
  __shared__ float part[4][2][32];
  if (lg == 0) {
    const float* u0 = vch + (size_t)b * 16;
    float s0 = 0.f;
    #pragma unroll
    for (int c = 0; c < 16; ++c) s0 += chi_first[r * 16 + c] * u0[c];
    v[bl][r] = s0;
  }
  __syncthreads();
  for (int s = 0; s < 62; ++s) {
    const float* u = vch + ((size_t)(s + 1) * 256 + b) * 16;
    float uc[16];
    #pragma unroll
    for (int c = 0; c < 16; ++c) uc[c] = u[c];
    const float* W = chi_mid + (size_t)s * 32 * 32 * 16;
    float sum = 0.f;
    #pragma unroll
    for (int j = 0; j < 16; ++j) {
      int l = lg * 16 + j;
      const float* Wl = W + ((size_t)l * 32 + r) * 16;
      float tt = 0.f;
      #pragma unroll
      for (int c = 0; c < 16; ++c) tt += Wl[c] * uc[c];
      sum += v[bl][l] * tt;
    }
    part[bl][lg][r] = sum;
    __syncthreads();
    if (lg == 0) v[bl][r] = part[bl][0][r] + part[bl][1][r];
    __syncthreads();
  }
  const float* u63 = vch + ((size_t)63 * 256 + b) * 16;
  float uc[16];
  #pragma unroll
  for (int c = 0; c < 16; ++c) uc[c] = u63[c];
  if (r < 10) {
    float acc = 0.f;
    #pragma unroll
    for (int j = 0; j < 16; ++j) {
      int l = lg * 16 + j;
      const float* cl = chi_last + (size_t)l * 16 * 10;
      float tt = 0.f;
      #pragma unroll
      for (int c = 0; c < 16; ++c) tt += cl[c * 10 + r] * uc[c];
      acc += v[bl][l] * tt;
    }
    part[bl][lg][r] = acc;
  }
  __syncthreads();
  if (lg == 0 && r < 10)
    out[b * 10 + r] = (part[bl][0][r] + part[bl][1][r]) * psiv[b] * phiv[0];
}

// ---------------------------------------------------------------------------
// Fallback (tiny workspace): per-b full psi chain from x directly.
__global__ __launch_bounds__(256) void k_psi_direct(const float* __restrict__ x,
                                                    const float* __restrict__ psi_mid,
                                                    const float* __restrict__ psi_first,
                                                    const float* __restrict__ psi_last,
                                                    float* __restrict__ psiv) {
  int b = blockIdx.x;
  int t = threadIdx.x;
  int r = t & 63, g = t >> 6;
  __shared__ float u[256];
  __shared__ float v[64];
  __shared__ float part[4][64];
  __shared__ float red[256];
  const float* xb = x + ((size_t)b << 18);
  {
    const float* rw = xb + (size_t)0 * 4096 + t * 16;
    float sm = 0.f;
    #pragma unroll
    for (int c = 0; c < 16; ++c) sm += rw[c];
    u[t] = sm * (1.0f / 16.0f);
  }
  __syncthreads();
  {
    float s0 = 0.f;
    for (int p = g * 64; p < g * 64 + 64; ++p) s0 += psi_first[r * 256 + p] * u[p];
    part[g][r] = s0;
    __syncthreads();
    if (g == 0) v[r] = part[0][r] + part[1][r] + part[2][r] + part[3][r];
  }
  __syncthreads();
  for (int s = 0; s < 62; ++s) {
    __syncthreads();
    {
      const float* rw = xb + (size_t)(s + 1) * 4096 + t * 16;
      float sm = 0.f;
      #pragma unroll
      for (int c = 0; c < 16; ++c) sm += rw[c];
      u[t] = sm * (1.0f / 16.0f);
    }
    __syncthreads();
    const float* W = psi_mid + (size_t)s * 4096 * 256;
    float sum = 0.f;
    for (int l = 0; l < 64; ++l) {
      const float* Wl = W + ((size_t)(l * 64 + r)) * 256 + g * 64;
      float tt = 0.f;
      #pragma unroll 8
      for (int k = 0; k < 64; ++k) tt += Wl[k] * u[g * 64 + k];
      sum += v[l] * tt;
    }
    part[g][r] = sum;
    __syncthreads();
    if (g == 0) v[r] = part[0][r] + part[1][r] + part[2][r] + part[3][r];
    __syncthreads();
  }
  __syncthreads();
  {
    const float* rw = xb + (size_t)63 * 4096 + t * 16;
    float sm = 0.f;
    #pragma unroll
    for (int c = 0; c < 16; ++c) sm += rw[c];
    u[t] = sm * (1.0f / 16.0f);
  }
  __syncthreads();
  float qv = 0.f;
  for (int l = 0; l < 64; ++l) qv += v[l] * psi_last[l * 256 + t];
  red[t] = qv * u[t];
  __syncthreads();
  for (int off = 128; off > 0; off >>= 1) {
    if (t < off) red[t] += red[t + off];
    __syncthreads();
  }
  if (t == 0) psiv[b] = red[0];
}

// ---------------------------------------------------------------------------
extern "C" void kernel_launch(void* const* d_in, const int* in_sizes, int n_in,
                              void* d_out, int out_size, void* d_ws, size_t ws_size,
                              hipStream_t stream) {
  const float* x         = (const float*)d_in[0];
  const float* chi_first = (const float*)d_in[1];
  const float* chi_mid   = (const float*)d_in[2];
  const float* chi_last  = (const float*)d_in[3];
  const float* psi_first = (const float*)d_in[4];
  const float* psi_mid   = (const float*)d_in[5];
  const float* psi_last  = (const float*)d_in[6];
  const float* phi_first = (const float*)d_in[7];
  const float* phi_mid   = (const float*)d_in[8];
  const float* phi_last  = (const float*)d_in[9];
  float* out = (float*)d_out;
  float* ws  = (float*)d_ws;

  size_t wsf = ws_size / 4;
  size_t off = 0;
  float* vch    = ws + off; off += (size_t)64 * 256 * 16;     // 262144
  float* psiv   = ws + off; off += 256;
  float* phisl  = ws + off; off += (size_t)62 * 64 * 64;      // 253952
  float* phiv   = ws + off; off += 16;
  float* vpsi   = ws + off; off += (size_t)64 * 256;          // 16384
  float* vchi   = ws + off; off += (size_t)32 * 256;          // 8192
  float* vpx    = ws + off; off += (size_t)64 * 256 * 256;    // 4194304
  unsigned short* vpxf_hi = (unsigned short*)(ws + off); off += (size_t)64 * 65536 / 2;
  unsigned short* vpxf_lo = (unsigned short*)(ws + off); off += (size_t)64 * 65536 / 2;
  float* Mbuf   = ws + off;                                   // shared by psi-M and chi-Tc
  size_t mfloats = (wsf > off) ? (wsf - off) : 0;
  int C = (int)(mfloats / ((size_t)256 * 4096));              // psi sites per chunk
  if (C > 62) C = 62;                                         // merge all: 1 gemm + 1 chain
  int Cc = (int)(mfloats / ((size_t)256 * 1024));             // chi sites per chunk
  if (Cc > 62) Cc = 62;
  bool pathA = (C >= 1);

  if (pathA) {
    k_reduce_x<<<16384 + 62, 256, 0, stream>>>(x, vch, vpx, vpxf_hi, vpxf_lo,
                                               phi_mid, phisl);
    // psi: chunked GEMM + chain (Mbuf holds C sites of M); C=62 when ws allows
    int done = 0;
    while (done < 62) {
      int c = imin(C, 62 - done);
      k_psi_gemm<<<dim3(64, 1, c), 512, 0, stream>>>(psi_mid, vpxf_hi, vpxf_lo, Mbuf, done);
      k_psi_chain<<<256, 256, 0, stream>>>(Mbuf, vpx, psi_first, psi_last,
                                           vpsi, psiv, c, (done == 0) ? 1 : 0,
                                           (done + c == 62) ? 1 : 0);
      done += c;
    }
    // chi: chunked contraction (phi chain fused into first chunk's dispatch)
    done = 0;
    while (done < 62) {
      int c = imin(Cc, 62 - done);
      int phiBlk = (done == 0) ? c : -1;
      int gx = (done == 0) ? (c + 1) : c;
      k_chi_gemm<<<dim3(gx, 8), 256, 0, stream>>>(chi_mid, vch, Mbuf, done, phiBlk,
                                                  phisl, phi_first, phi_last, phiv);
      k_chi_chain<<<256, 64, 0, stream>>>(Mbuf, chi_first, chi_last, vch,
                                          psiv, phiv, vchi, out, c,
                                          (done == 0) ? 1 : 0,
                                          (done + c == 62) ? 1 : 0);
      done += c;
    }
  } else {
    k_reduce_x<<<16384 + 62, 256, 0, stream>>>(x, vch, nullptr, nullptr, nullptr,
                                               phi_mid, phisl);
    k_psi_direct<<<256, 256, 0, stream>>>(x, psi_mid, psi_first, psi_last, psiv);
    k_phi_chain<<<1, 256, 0, stream>>>(phisl, phi_first, phi_last, phiv);
    k_chi_fused<<<64, 256, 0, stream>>>(chi_first, chi_mid, chi_last, vch, psiv, phiv, out);
  }
}